// Round 11
// baseline (184.501 us; speedup 1.0000x reference)
//
#include <hip/hip_runtime.h>
#include <math.h>
#include <limits.h>

#define NB 16
#define NC 21
#define NANCH 65536
#define NM 20

#define POS_THR 0.5f
#define NEG_THR 0.4f
#define F_ALPHA 0.25f
#define MIN_POS_TOPK 10
#define NEG_POS_RATIO 3

#define SBINS 256            // score bins: (unsigned)(s*256.0f), exact & monotone
#define QBINS 1024           // iou bins:   (unsigned)(q*1024.0f), exact & monotone
#define EQCAP 2048
#define QCAP  8192
#define APT 4
#define IOU_TPB 512
#define IOU_BPI 32           // 65536 / (512*4)

__device__ __forceinline__ unsigned score_bin(float s) {
  unsigned b = (unsigned)(s * 256.0f);
  return b > (SBINS - 1) ? (SBINS - 1) : b;
}
__device__ __forceinline__ unsigned q_bin(float q) {
  unsigned b = (unsigned)(q * 1024.0f);
  return b > (QBINS - 1) ? (QBINS - 1) : b;
}

// ---------- K0: zero hists + scalar accumulators ----------
__global__ void k_init(unsigned* qhist, unsigned* shist,
                       int* pos_cnt, int* neg_cnt,
                       int* eqcnt, int* qcnt, float* sums) {
  size_t tid = (size_t)blockIdx.x * blockDim.x + threadIdx.x;
  size_t tq = (size_t)NB * QBINS;
  size_t ts = (size_t)NB * SBINS;
  for (size_t j = tid; j < tq; j += (size_t)gridDim.x * blockDim.x) qhist[j] = 0u;
  for (size_t j = tid; j < ts; j += (size_t)gridDim.x * blockDim.x) shist[j] = 0u;
  if (blockIdx.x == 0) {
    int t = threadIdx.x;
    if (t < NB) { pos_cnt[t] = 0; neg_cnt[t] = 0; eqcnt[t] = 0; qcnt[t] = 0; }
    if (t < 3 * NB) sums[t] = 0.0f;
  }
}

// ---------- K1: decode + IoU max/argmax + counts + LDS hists ----------
__global__ __launch_bounds__(IOU_TPB)
void k_iou(const float* __restrict__ reg, const float* __restrict__ anchors,
           const float* __restrict__ tb, const float* __restrict__ scores,
           float* __restrict__ miou, int* __restrict__ midx,
           int* __restrict__ pos_cnt, int* __restrict__ neg_cnt,
           unsigned* __restrict__ qhist, unsigned* __restrict__ shist) {
  __shared__ float4 tbs4[NM];
  __shared__ float  tarea[NM];
  __shared__ unsigned lsh[SBINS];
  __shared__ unsigned lqh[QBINS];
  int b   = blockIdx.x >> 5;            // 32 blocks per image
  int blk = blockIdx.x & 31;
  int n0  = (blk << 11) + threadIdx.x;  // 2048 anchors per block
  if (threadIdx.x < NM) {
    float4 t4 = ((const float4*)tb)[b * NM + threadIdx.x];
    tbs4[threadIdx.x] = t4;
    tarea[threadIdx.x] = (t4.z - t4.x) * (t4.w - t4.y);
  }
  if (threadIdx.x < SBINS) lsh[threadIdx.x] = 0u;
  for (int j = threadIdx.x; j < QBINS; j += IOU_TPB) lqh[j] = 0u;
  __syncthreads();

  // ---- decode 4 anchors ----
  float dv[APT][4];
  float areaA[APT];
  #pragma unroll
  for (int j = 0; j < APT; ++j) {
    int n = n0 + j * IOU_TPB;
    float4 a4 = ((const float4*)anchors)[n];
    float aw = a4.z - a4.x, ah = a4.w - a4.y;
    float acx = a4.x + 0.5f * aw, acy = a4.y + 0.5f * ah;
    size_t rb = ((size_t)b * 4) * NANCH + n;
    float rx = reg[rb];
    float ry = reg[rb + (size_t)NANCH];
    float rw = reg[rb + 2 * (size_t)NANCH];
    float rh = reg[rb + 3 * (size_t)NANCH];
    float cx = acx + rx * aw, cy = acy + ry * ah;
    float w = aw * expf(rw), h = ah * expf(rh);
    dv[j][0] = cx - 0.5f * w;
    dv[j][1] = cy - 0.5f * h;
    dv[j][2] = cx + 0.5f * w;
    dv[j][3] = cy + 0.5f * h;
    areaA[j] = (dv[j][2] - dv[j][0]) * (dv[j][3] - dv[j][1]);
  }

  // ---- cross-mult argmax over 20 boxes (m outer, anchors inner) ----
  float bI[APT], bU[APT];
  int   bM[APT];
  {
    float4 t = tbs4[0];
    float ab = tarea[0];
    #pragma unroll
    for (int j = 0; j < APT; ++j) {
      float lx = fmaxf(dv[j][0], t.x), ly = fmaxf(dv[j][1], t.y);
      float rx2 = fminf(dv[j][2], t.z), ry2 = fminf(dv[j][3], t.w);
      float iw = fmaxf(rx2 - lx, 0.0f), ih = fmaxf(ry2 - ly, 0.0f);
      float inter = iw * ih;
      bI[j] = inter;
      bU[j] = areaA[j] + ab - inter;
      bM[j] = 0;
    }
  }
  #pragma unroll
  for (int m = 1; m < NM; ++m) {
    float4 t = tbs4[m];
    float ab = tarea[m];
    #pragma unroll
    for (int j = 0; j < APT; ++j) {
      float lx = fmaxf(dv[j][0], t.x), ly = fmaxf(dv[j][1], t.y);
      float rx2 = fminf(dv[j][2], t.z), ry2 = fminf(dv[j][3], t.w);
      float iw = fmaxf(rx2 - lx, 0.0f), ih = fmaxf(ry2 - ly, 0.0f);
      float inter = iw * ih;
      float uni = areaA[j] + ab - inter;
      // inter/uni > bI/bU  <=>  inter*bU > bI*uni  (both unions > 0)
      if (inter * bU[j] > bI[j] * uni) { bI[j] = inter; bU[j] = uni; bM[j] = m; }
    }
  }

  // ---- finalize miou/midx, counts, LDS hists ----
  int lane = threadIdx.x & 63;
  int cp = 0, cn = 0;
  #pragma unroll
  for (int j = 0; j < APT; ++j) {
    int n = n0 + j * IOU_TPB;
    size_t idx = (size_t)b * NANCH + n;
    float q = bI[j] / fmaxf(bU[j], 1e-7f);   // IEEE, matches reference
    miou[idx] = q;
    midx[idx] = bM[j];
    bool p  = (q >= POS_THR);
    bool ng = (q < NEG_THR);
    cp += __popcll(__ballot(p));
    cn += __popcll(__ballot(ng));
    // q-hist: batch the q==0 mass per wave (avoids same-address LDS atomic storm)
    unsigned long long zm = __ballot(q == 0.0f);
    if (lane == 0 && zm) atomicAdd(&lqh[0], (unsigned)__popcll(zm));
    if (q != 0.0f) atomicAdd(&lqh[q_bin(q)], 1u);
    float sc = scores[idx];
    if (ng) atomicAdd(&lsh[score_bin(sc)], 1u);
  }
  if (lane == 0) {
    if (cp) atomicAdd(&pos_cnt[b], cp);
    if (cn) atomicAdd(&neg_cnt[b], cn);
  }

  // ---- flush LDS hists ----
  __syncthreads();
  if (threadIdx.x < SBINS) {
    unsigned c = lsh[threadIdx.x];
    if (c) atomicAdd(&shist[b * SBINS + threadIdx.x], c);
  }
  for (int j = threadIdx.x; j < QBINS; j += IOU_TPB) {
    unsigned c = lqh[j];
    if (c) atomicAdd(&qhist[b * QBINS + j], c);
  }
}

// ---------- K2: blocks 0..15 q-threshold-bin pick, 16..31 score bucket pick ----------
__global__ __launch_bounds__(256)
void k_mid(const unsigned* __restrict__ qhist, const unsigned* __restrict__ shist,
           const int* __restrict__ pos_cnt, const int* __restrict__ neg_cnt,
           int* __restrict__ num_pos, int* __restrict__ use_fb,
           int* __restrict__ qtb,
           int* __restrict__ subsample, int* __restrict__ bucket,
           int* __restrict__ below, int* __restrict__ total_samples) {
  if (blockIdx.x < NB) {
    int b = blockIdx.x;
    __shared__ unsigned h[QBINS];
    for (int j = threadIdx.x; j < QBINS; j += 256) h[j] = qhist[(size_t)b * QBINS + j];
    __syncthreads();
    if (threadIdx.x == 0) {
      // smallest bin t (scanning from the top) with count(qbin >= t) >= 10
      unsigned cum = 0;
      int t = 0;
      for (int i = QBINS - 1; i >= 0; --i) {
        if (cum + h[i] >= (unsigned)MIN_POS_TOPK) { t = i; break; }
        cum += h[i];
      }
      qtb[b] = t;
      int pc = pos_cnt[b];
      int fb = (pc < MIN_POS_TOPK) ? 1 : 0;
      use_fb[b] = fb;
      num_pos[b] = fb ? MIN_POS_TOPK : pc;
    }
  } else {
    int b = blockIdx.x - NB;
    int pc = pos_cnt[b];
    int np = (pc < MIN_POS_TOPK) ? MIN_POS_TOPK : pc;
    int nc = neg_cnt[b];
    int k = NEG_POS_RATIO * np;
    if (nc <= k) {
      if (threadIdx.x == 0) {
        subsample[b] = 0;
        bucket[b] = -1;
        below[b] = 0;
        total_samples[b] = np + nc;
      }
      return;
    }
    __shared__ unsigned psum[SBINS];
    if (threadIdx.x < SBINS) psum[threadIdx.x] = shist[(size_t)b * SBINS + threadIdx.x];
    __syncthreads();
    if (threadIdx.x == 0) {
      unsigned cum = 0;
      int bkt = SBINS - 1;
      for (int t = 0; t < SBINS; ++t) {
        if (cum + psum[t] >= (unsigned)k) { bkt = t; break; }
        cum += psum[t];
      }
      subsample[b] = 1;
      bucket[b] = bkt;
      below[b] = (int)cum;
      total_samples[b] = np + k;
    }
  }
}

// ---------- K3: gather q-candidates + score-boundary elements ----------
__global__ __launch_bounds__(256)
void k_gather(const float* __restrict__ miou, const float* __restrict__ scores,
              const int* __restrict__ qtb,
              const int* __restrict__ subsample, const int* __restrict__ bucket,
              unsigned* __restrict__ qcb, int* __restrict__ qci, int* __restrict__ qcnt,
              unsigned* __restrict__ eqb, int* __restrict__ eqi, int* __restrict__ eqcnt) {
  int b = blockIdx.x >> 8;
  int n = ((blockIdx.x & 255) << 8) | threadIdx.x;
  size_t idx = (size_t)b * NANCH + n;
  float mi = miou[idx];
  if ((int)q_bin(mi) >= qtb[b]) {
    int slot = atomicAdd(&qcnt[b], 1);
    if (slot < QCAP) {
      qcb[(size_t)b * QCAP + slot] = __float_as_uint(mi);  // mi >= 0: bit order == value order
      qci[(size_t)b * QCAP + slot] = n;
    }
  }
  if (mi < NEG_THR && subsample[b]) {
    float sc = scores[idx];
    if ((int)score_bin(sc) == bucket[b]) {
      int slot = atomicAdd(&eqcnt[b], 1);
      if (slot < EQCAP) {
        eqb[(size_t)b * EQCAP + slot] = __float_as_uint(sc);
        eqi[(size_t)b * EQCAP + slot] = n;
      }
    }
  }
}

// ---------- K4: blocks 0..15 exact top-10, 16..31 exact negative cut ----------
__global__ __launch_bounds__(256)
void k_sel(const unsigned* __restrict__ qcb, const int* __restrict__ qci,
           const int* __restrict__ qcnt,
           const unsigned* __restrict__ eqb, const int* __restrict__ eqi,
           const int* __restrict__ eqcnt,
           const int* __restrict__ subsample, const int* __restrict__ num_pos,
           const int* __restrict__ below,
           const float* __restrict__ miou,
           int* __restrict__ top10,
           unsigned* __restrict__ vbits_out, int* __restrict__ idx_cut) {
  if (blockIdx.x < NB) {
    int b = blockIdx.x;
    int E = qcnt[b];
    if (E <= QCAP) {
      const unsigned* qb_ = qcb + (size_t)b * QCAP;
      const int*      qi_ = qci + (size_t)b * QCAP;
      for (int e = threadIdx.x; e < E; e += 256) {
        unsigned mb = qb_[e]; int mi_ = qi_[e];
        int rank = 0;
        for (int j = 0; j < E; ++j) {
          unsigned ob = qb_[j]; int oi = qi_[j];
          rank += (ob > mb || (ob == mb && oi < mi_)) ? 1 : 0;
        }
        if (rank < MIN_POS_TOPK) top10[b * MIN_POS_TOPK + rank] = mi_;
      }
    } else {
      // fallback (never expected): exact 10-iteration scan over miou
      const float* mi = miou + (size_t)b * NANCH;
      __shared__ float sv[256];
      __shared__ int   si[256];
      __shared__ int   sel[MIN_POS_TOPK];
      for (int it = 0; it < MIN_POS_TOPK; ++it) {
        float bv = -1.0f; int bi = NANCH;
        for (int n = threadIdx.x; n < NANCH; n += 256) {
          bool skip = false;
          for (int s = 0; s < it; ++s) if (sel[s] == n) skip = true;
          if (skip) continue;
          float v = mi[n];
          if (v > bv || (v == bv && n < bi)) { bv = v; bi = n; }
        }
        sv[threadIdx.x] = bv; si[threadIdx.x] = bi;
        __syncthreads();
        if (threadIdx.x == 0) {
          float bestv = -1.0f; int besti = NANCH;
          for (int t = 0; t < 256; ++t) {
            if (sv[t] > bestv || (sv[t] == bestv && si[t] < besti)) { bestv = sv[t]; besti = si[t]; }
          }
          sel[it] = besti;
        }
        __syncthreads();
      }
      if (threadIdx.x < MIN_POS_TOPK) top10[b * MIN_POS_TOPK + threadIdx.x] = sel[threadIdx.x];
    }
  } else {
    int b = blockIdx.x - NB;
    if (!subsample[b]) {
      if (threadIdx.x == 0) { vbits_out[b] = 0u; idx_cut[b] = -1; }
      return;
    }
    int E = eqcnt[b]; if (E > EQCAP) E = EQCAP;
    int r = NEG_POS_RATIO * num_pos[b] - below[b];   // 1-based rank within bucket
    __shared__ unsigned sb_[EQCAP];
    __shared__ int      si_[EQCAP];
    for (int j = threadIdx.x; j < E; j += 256) {
      sb_[j] = eqb[(size_t)b * EQCAP + j];
      si_[j] = eqi[(size_t)b * EQCAP + j];
    }
    __syncthreads();
    for (int e = threadIdx.x; e < E; e += 256) {
      unsigned mb = sb_[e]; int mi = si_[e];
      int rank = 0;
      for (int j = 0; j < E; ++j) {
        unsigned ob = sb_[j]; int oi = si_[j];
        rank += (ob < mb || (ob == mb && oi < mi)) ? 1 : 0;
      }
      if (rank == r - 1) { vbits_out[b] = mb; idx_cut[b] = mi; }
    }
  }
}

// ---------- K5: per-anchor loss accumulation ----------
__global__ __launch_bounds__(256)
void k_loss(const float* __restrict__ cls, const float* __restrict__ reg,
            const float* __restrict__ anchors, const float* __restrict__ tb,
            const int* __restrict__ tl, const float* __restrict__ scores,
            const float* __restrict__ miou, const int* __restrict__ midx,
            const int* __restrict__ use_fb, const int* __restrict__ top10,
            const int* __restrict__ subsample, const unsigned* __restrict__ vbits,
            const int* __restrict__ idx_cut,
            float* __restrict__ sums /* [NB][3] : pos, neg, reg */) {
  int b = blockIdx.x >> 8;
  int n = ((blockIdx.x & 255) << 8) | threadIdx.x;
  __shared__ int s_top10[MIN_POS_TOPK];
  __shared__ int s_usefb, s_sub, s_cut;
  __shared__ unsigned s_vb;
  __shared__ float accp, accn, accr;
  if (threadIdx.x < MIN_POS_TOPK) s_top10[threadIdx.x] = top10[b * MIN_POS_TOPK + threadIdx.x];
  if (threadIdx.x == 0) {
    s_usefb = use_fb[b]; s_sub = subsample[b]; s_cut = idx_cut[b]; s_vb = vbits[b];
    accp = 0.0f; accn = 0.0f; accr = 0.0f;
  }
  __syncthreads();

  size_t idx = (size_t)b * NANCH + n;
  float mi = miou[idx];

  bool pos;
  if (s_usefb) {
    pos = false;
    #pragma unroll
    for (int i = 0; i < MIN_POS_TOPK; ++i) pos |= (s_top10[i] == n);
  } else {
    pos = (mi >= POS_THR);
  }
  bool neg = (mi < NEG_THR);
  bool nsel = false;
  if (neg) {
    if (!s_sub) nsel = true;
    else {
      unsigned sb = __float_as_uint(scores[idx]);
      nsel = (sb < s_vb) || (sb == s_vb && n <= s_cut);
    }
  }

  float cp = 0.0f, cn = 0.0f, rg = 0.0f;
  if (pos || nsel) {
    int mx = 0, t = 0;
    if (pos) { mx = midx[idx]; t = tl[b * NM + mx]; }
    size_t cb = ((size_t)b * NC) * NANCH + n;
    float mxl = -3.0e38f, l0 = 0.0f, lt = 0.0f;
    for (int c = 0; c < NC; ++c) {
      float l = cls[cb + (size_t)c * NANCH];
      if (c == 0) l0 = l;
      if (c == t) lt = l;
      mxl = fmaxf(mxl, l);
    }
    float se = 0.0f;
    for (int c = 0; c < NC; ++c) {
      float l = cls[cb + (size_t)c * NANCH];
      se += expf(l - mxl);
    }
    float lse = mxl + logf(se);
    if (nsel) {
      float ce = lse - l0;
      float pt = expf(-ce);
      float om = 1.0f - pt;
      cn = F_ALPHA * om * om * ce;
    }
    if (pos) {
      float ce = lse - lt;
      float pt = expf(-ce);
      float om = 1.0f - pt;
      cp = F_ALPHA * om * om * ce;
      // decode + GIoU vs matched GT
      const float4 a4 = ((const float4*)anchors)[n];
      float aw = a4.z - a4.x, ah = a4.w - a4.y;
      float acx = a4.x + 0.5f * aw, acy = a4.y + 0.5f * ah;
      size_t rb = ((size_t)b * 4) * NANCH + n;
      float rx = reg[rb];
      float ry = reg[rb + (size_t)NANCH];
      float rw = reg[rb + 2 * (size_t)NANCH];
      float rh = reg[rb + 3 * (size_t)NANCH];
      float ccx = acx + rx * aw, ccy = acy + ry * ah;
      float w = aw * expf(rw), h = ah * expf(rh);
      float d0 = ccx - 0.5f * w, d1 = ccy - 0.5f * h;
      float d2 = ccx + 0.5f * w, d3 = ccy + 0.5f * h;
      const float* g = tb + ((size_t)b * NM + mx) * 4;
      float gx1 = g[0], gy1 = g[1], gx2 = g[2], gy2 = g[3];
      float area_a = (d2 - d0) * (d3 - d1);
      float area_b = (gx2 - gx1) * (gy2 - gy1);
      float lx = fmaxf(d0, gx1), ly = fmaxf(d1, gy1);
      float rx2 = fminf(d2, gx2), ry2 = fminf(d3, gy2);
      float iw = fmaxf(rx2 - lx, 0.0f), ih = fmaxf(ry2 - ly, 0.0f);
      float inter = iw * ih;
      float uni = area_a + area_b - inter;
      float iou = inter / fmaxf(uni, 1e-7f);
      float ex1 = fminf(d0, gx1), ey1 = fminf(d1, gy1);
      float ex2 = fmaxf(d2, gx2), ey2 = fmaxf(d3, gy2);
      float ew = fmaxf(ex2 - ex1, 0.0f), eh = fmaxf(ey2 - ey1, 0.0f);
      float enc = ew * eh;
      float giou = iou - (enc - uni) / fmaxf(enc, 1e-7f);
      rg = 1.0f - giou;
    }
  }

  if (cp != 0.0f) atomicAdd(&accp, cp);
  if (cn != 0.0f) atomicAdd(&accn, cn);
  if (rg != 0.0f) atomicAdd(&accr, rg);
  __syncthreads();
  if (threadIdx.x == 0) {
    if (accp != 0.0f) atomicAdd(&sums[b * 3 + 0], accp);
    if (accn != 0.0f) atomicAdd(&sums[b * 3 + 1], accn);
    if (accr != 0.0f) atomicAdd(&sums[b * 3 + 2], accr);
  }
}

// ---------- K6: finalize (parallel, 64 threads) ----------
__global__ void k_final(const float* __restrict__ sums,
                        const int* __restrict__ total_samples,
                        const int* __restrict__ num_pos,
                        float* __restrict__ out) {
  int t = threadIdx.x;
  float cm = 0.0f, rm = 0.0f;
  if (t < NB) {
    int ts = total_samples[t]; if (ts < 1) ts = 1;
    int np = num_pos[t]; if (np < 1) np = 1;
    cm = (sums[t * 3 + 0] + sums[t * 3 + 1]) / (float)ts;
    rm = sums[t * 3 + 2] / (float)np;
  }
  #pragma unroll
  for (int m = 8; m >= 1; m >>= 1) {
    cm += __shfl_down(cm, m, 64);
    rm += __shfl_down(rm, m, 64);
  }
  if (t == 0) out[0] = cm / (float)NB + rm / (float)NB;
}

extern "C" void kernel_launch(void* const* d_in, const int* in_sizes, int n_in,
                              void* d_out, int out_size, void* d_ws, size_t ws_size,
                              hipStream_t stream) {
  const float* cls     = (const float*)d_in[0];
  const float* reg     = (const float*)d_in[1];
  const float* anchors = (const float*)d_in[2];
  const float* tb      = (const float*)d_in[3];
  const int*   tl      = (const int*)d_in[4];
  const float* scores  = (const float*)d_in[5];
  float* out = (float*)d_out;

  char* ws = (char*)d_ws;
  size_t off = 0;
  float* miou = (float*)(ws + off);            off += (size_t)4 * NB * NANCH;
  int*   midx = (int*)(ws + off);              off += (size_t)4 * NB * NANCH;
  unsigned* qhist = (unsigned*)(ws + off);     off += (size_t)4 * NB * QBINS;
  unsigned* shist = (unsigned*)(ws + off);     off += (size_t)4 * NB * SBINS;
  unsigned* qcb = (unsigned*)(ws + off);       off += (size_t)4 * NB * QCAP;
  int*   qci = (int*)(ws + off);               off += (size_t)4 * NB * QCAP;
  unsigned* eqb = (unsigned*)(ws + off);       off += (size_t)4 * NB * EQCAP;
  int*   eqi = (int*)(ws + off);               off += (size_t)4 * NB * EQCAP;
  int* scal = (int*)(ws + off);
  int* pos_cnt       = scal;
  int* neg_cnt       = scal + NB;
  int* num_pos       = scal + 2 * NB;
  int* use_fb        = scal + 3 * NB;
  int* subsample     = scal + 4 * NB;
  int* idx_cut       = scal + 5 * NB;
  unsigned* vbits    = (unsigned*)(scal + 6 * NB);
  int* total_samples = scal + 7 * NB;
  int* bucket        = scal + 8 * NB;
  int* below         = scal + 9 * NB;
  int* eqcnt         = scal + 10 * NB;
  int* qcnt          = scal + 11 * NB;
  int* qtb           = scal + 12 * NB;
  int* top10         = scal + 13 * NB;                         // NB*10
  float* sums        = (float*)(scal + 13 * NB + MIN_POS_TOPK * NB); // NB*3

  k_init<<<32, 256, 0, stream>>>(qhist, shist, pos_cnt, neg_cnt, eqcnt, qcnt, sums);
  k_iou<<<NB * IOU_BPI, IOU_TPB, 0, stream>>>(reg, anchors, tb, scores, miou, midx,
                                              pos_cnt, neg_cnt, qhist, shist);
  k_mid<<<2 * NB, 256, 0, stream>>>(qhist, shist, pos_cnt, neg_cnt,
                                    num_pos, use_fb, qtb,
                                    subsample, bucket, below, total_samples);
  k_gather<<<NB * 256, 256, 0, stream>>>(miou, scores, qtb, subsample, bucket,
                                         qcb, qci, qcnt, eqb, eqi, eqcnt);
  k_sel<<<2 * NB, 256, 0, stream>>>(qcb, qci, qcnt, eqb, eqi, eqcnt,
                                    subsample, num_pos, below, miou,
                                    top10, vbits, idx_cut);
  k_loss<<<NB * 256, 256, 0, stream>>>(cls, reg, anchors, tb, tl, scores,
                                       miou, midx, use_fb, top10, subsample,
                                       vbits, idx_cut, sums);
  k_final<<<1, 64, 0, stream>>>(sums, total_samples, num_pos, out);
}

// Round 13
// 119.421 us; speedup vs baseline: 1.5450x; 1.5450x over previous
//
#include <hip/hip_runtime.h>
#include <math.h>
#include <limits.h>

#define NB 16
#define NC 21
#define NANCH 65536
#define NM 20

#define POS_THR 0.5f
#define NEG_THR 0.4f
#define F_ALPHA 0.25f
#define MIN_POS_TOPK 10
#define NEG_POS_RATIO 3

#define SBINS 256       // score bins: (unsigned)(s*256.0f), exact & monotone
#define QBINS 1024      // iou bins:   (unsigned)(q*1024.0f), exact & monotone
#define EQCAP 2048      // LDS cap: boundary-bucket list
#define QCCAP 1024      // LDS cap: top-10 candidate list
#define APT 2
#define IOU_TPB 256
#define SEL_TPB 1024

__device__ __forceinline__ unsigned score_bin(float s) {
  unsigned b = (unsigned)(s * 256.0f);
  return b > (SBINS - 1) ? (SBINS - 1) : b;
}
__device__ __forceinline__ unsigned q_bin(float q) {
  unsigned b = (unsigned)(q * 1024.0f);
  return b > (QBINS - 1) ? (QBINS - 1) : b;
}

// ---------- K1: pure decode + IoU max/argmax (no atomics, no hists) ----------
__global__ __launch_bounds__(IOU_TPB)
void k_iou(const float* __restrict__ reg, const float* __restrict__ anchors,
           const float* __restrict__ tb,
           float* __restrict__ miou, int* __restrict__ midx) {
  __shared__ float4 tbs4[NM];
  __shared__ float  tarea[NM];
  int b   = blockIdx.x >> 7;           // 128 blocks per image
  int blk = blockIdx.x & 127;
  int n0  = (blk << 9) + threadIdx.x;  // 512 anchors per block
  if (threadIdx.x < NM) {
    float4 t4 = ((const float4*)tb)[b * NM + threadIdx.x];
    tbs4[threadIdx.x] = t4;
    tarea[threadIdx.x] = (t4.z - t4.x) * (t4.w - t4.y);
  }
  __syncthreads();

  float dv[APT][4];
  float areaA[APT];
  #pragma unroll
  for (int j = 0; j < APT; ++j) {
    int n = n0 + j * IOU_TPB;
    float4 a4 = ((const float4*)anchors)[n];
    float aw = a4.z - a4.x, ah = a4.w - a4.y;
    float acx = a4.x + 0.5f * aw, acy = a4.y + 0.5f * ah;
    size_t rb = ((size_t)b * 4) * NANCH + n;
    float rx = reg[rb];
    float ry = reg[rb + (size_t)NANCH];
    float rw = reg[rb + 2 * (size_t)NANCH];
    float rh = reg[rb + 3 * (size_t)NANCH];
    float cx = acx + rx * aw, cy = acy + ry * ah;
    float w = aw * expf(rw), h = ah * expf(rh);
    dv[j][0] = cx - 0.5f * w;
    dv[j][1] = cy - 0.5f * h;
    dv[j][2] = cx + 0.5f * w;
    dv[j][3] = cy + 0.5f * h;
    areaA[j] = (dv[j][2] - dv[j][0]) * (dv[j][3] - dv[j][1]);
  }

  float bI[APT], bU[APT];
  int   bM[APT];
  {
    float4 t = tbs4[0];
    float ab = tarea[0];
    #pragma unroll
    for (int j = 0; j < APT; ++j) {
      float lx = fmaxf(dv[j][0], t.x), ly = fmaxf(dv[j][1], t.y);
      float rx2 = fminf(dv[j][2], t.z), ry2 = fminf(dv[j][3], t.w);
      float iw = fmaxf(rx2 - lx, 0.0f), ih = fmaxf(ry2 - ly, 0.0f);
      float inter = iw * ih;
      bI[j] = inter;
      bU[j] = areaA[j] + ab - inter;
      bM[j] = 0;
    }
  }
  #pragma unroll
  for (int m = 1; m < NM; ++m) {
    float4 t = tbs4[m];
    float ab = tarea[m];
    #pragma unroll
    for (int j = 0; j < APT; ++j) {
      float lx = fmaxf(dv[j][0], t.x), ly = fmaxf(dv[j][1], t.y);
      float rx2 = fminf(dv[j][2], t.z), ry2 = fminf(dv[j][3], t.w);
      float iw = fmaxf(rx2 - lx, 0.0f), ih = fmaxf(ry2 - ly, 0.0f);
      float inter = iw * ih;
      float uni = areaA[j] + ab - inter;
      // inter/uni > bI/bU  <=>  inter*bU > bI*uni (both unions > 0)
      if (inter * bU[j] > bI[j] * uni) { bI[j] = inter; bU[j] = uni; bM[j] = m; }
    }
  }

  #pragma unroll
  for (int j = 0; j < APT; ++j) {
    int n = n0 + j * IOU_TPB;
    size_t idx = (size_t)b * NANCH + n;
    miou[idx] = bI[j] / fmaxf(bU[j], 1e-7f);   // IEEE, matches reference
    midx[idx] = bM[j];
  }
}

// ---------- K2: fused per-image selection (hist + thresholds + gather + rank) ----------
__global__ __launch_bounds__(SEL_TPB)
void k_select(const float* __restrict__ miou, const float* __restrict__ scores,
              int* __restrict__ num_pos, int* __restrict__ use_fb,
              int* __restrict__ subsample, int* __restrict__ total_samples,
              int* __restrict__ top10,
              unsigned* __restrict__ vbits_out, int* __restrict__ idx_cut,
              float* __restrict__ sums) {
  int b = blockIdx.x;
  const float* mi = miou + (size_t)b * NANCH;
  const float* sc = scores + (size_t)b * NANCH;

  __shared__ unsigned lqh[QBINS];
  __shared__ unsigned lsh[SBINS];
  __shared__ unsigned segsum[QBINS / 4];
  __shared__ int redcp[SEL_TPB / 64], redcn[SEL_TPB / 64];
  __shared__ unsigned s_qtb, s_bkt, s_below, s_k;
  __shared__ int s_sub;
  __shared__ int qcn, eqn;
  __shared__ unsigned qcb_[QCCAP];
  __shared__ int      qci_[QCCAP];
  __shared__ unsigned eqb_[EQCAP];
  __shared__ int      eqi_[EQCAP];
  __shared__ float fsv[SEL_TPB / 64];
  __shared__ int   fsi[SEL_TPB / 64];
  __shared__ int   fsel[MIN_POS_TOPK];

  for (int j = threadIdx.x; j < QBINS; j += SEL_TPB) lqh[j] = 0u;
  if (threadIdx.x < SBINS) lsh[threadIdx.x] = 0u;
  if (threadIdx.x == 0) { qcn = 0; eqn = 0; }
  __syncthreads();

  int lane = threadIdx.x & 63;
  int wid  = threadIdx.x >> 6;

  // ---- phase 1: hists + pos/neg counts ----
  int cp = 0, cn = 0;
  for (int i = 0; i < NANCH / SEL_TPB; ++i) {
    int n = i * SEL_TPB + threadIdx.x;
    float q = mi[n];
    bool p  = (q >= POS_THR);
    bool ng = (q < NEG_THR);
    cp += p ? 1 : 0;
    cn += ng ? 1 : 0;
    unsigned long long zm = __ballot(q == 0.0f);
    if (q != 0.0f) atomicAdd(&lqh[q_bin(q)], 1u);
    else if (lane == __ffsll(zm) - 1) atomicAdd(&lqh[0], (unsigned)__popcll(zm));
    if (ng) atomicAdd(&lsh[score_bin(sc[n])], 1u);
  }
  #pragma unroll
  for (int m = 32; m >= 1; m >>= 1) {
    cp += __shfl_down(cp, m, 64);
    cn += __shfl_down(cn, m, 64);
  }
  if (lane == 0) { redcp[wid] = cp; redcn[wid] = cn; }
  __syncthreads();
  if (threadIdx.x < QBINS / 4) {
    int s4 = threadIdx.x * 4;
    segsum[threadIdx.x] = lqh[s4] + lqh[s4 + 1] + lqh[s4 + 2] + lqh[s4 + 3];
  }
  __syncthreads();

  if (threadIdx.x == 0) {
    int pc = 0, nc = 0;
    for (int w = 0; w < SEL_TPB / 64; ++w) { pc += redcp[w]; nc += redcn[w]; }
    int fb = (pc < MIN_POS_TOPK) ? 1 : 0;
    int np = fb ? MIN_POS_TOPK : pc;
    int k = NEG_POS_RATIO * np;
    // q-threshold: smallest bin t with count(qbin >= t) >= 10 (scan from top)
    unsigned cum = 0; int t = 0; bool found = false;
    for (int s = QBINS / 4 - 1; s >= 0 && !found; --s) {
      if (cum + segsum[s] >= (unsigned)MIN_POS_TOPK) {
        for (int i2 = 3; i2 >= 0; --i2) {
          int bin = s * 4 + i2;
          if (cum + lqh[bin] >= (unsigned)MIN_POS_TOPK) { t = bin; found = true; break; }
          cum += lqh[bin];
        }
      } else cum += segsum[s];
    }
    s_qtb = (unsigned)t;
    // score bucket for negative subsampling
    int sub; unsigned below = 0; int bkt = -1;
    if (nc <= k) {
      sub = 0;
      total_samples[b] = np + nc;
    } else {
      sub = 1;
      unsigned c2 = 0; int bk = SBINS - 1;
      for (int ti = 0; ti < SBINS; ++ti) {
        if (c2 + lsh[ti] >= (unsigned)k) { bk = ti; break; }
        c2 += lsh[ti];
      }
      bkt = bk; below = c2;
      total_samples[b] = np + k;
    }
    s_sub = sub; s_bkt = (unsigned)bkt; s_below = below; s_k = (unsigned)k;
    num_pos[b] = np; use_fb[b] = fb; subsample[b] = sub;
    sums[b * 3 + 0] = 0.0f; sums[b * 3 + 1] = 0.0f; sums[b * 3 + 2] = 0.0f;
    if (!sub) { vbits_out[b] = 0u; idx_cut[b] = -1; }
  }
  __syncthreads();

  // ---- phase 2: gather candidate lists into LDS ----
  int qtbv = (int)s_qtb;
  int sub  = s_sub;
  int bktv = (int)s_bkt;
  for (int i = 0; i < NANCH / SEL_TPB; ++i) {
    int n = i * SEL_TPB + threadIdx.x;
    float q = mi[n];
    if ((int)q_bin(q) >= qtbv) {
      int slot = atomicAdd(&qcn, 1);
      if (slot < QCCAP) { qcb_[slot] = __float_as_uint(q); qci_[slot] = n; }
    }
    if (sub && q < NEG_THR) {
      float s = sc[n];
      if ((int)score_bin(s) == bktv) {
        int slot = atomicAdd(&eqn, 1);
        if (slot < EQCAP) { eqb_[slot] = __float_as_uint(s); eqi_[slot] = n; }
      }
    }
  }
  __syncthreads();

  // ---- phase 3a: exact top-10 (value desc, index asc) ----
  int E = qcn;
  if (E <= QCCAP) {
    for (int e = threadIdx.x; e < E; e += SEL_TPB) {
      unsigned mb = qcb_[e]; int mi_ = qci_[e];
      int rank = 0;
      for (int j = 0; j < E; ++j) {
        unsigned ob = qcb_[j]; int oi = qci_[j];
        rank += (ob > mb || (ob == mb && oi < mi_)) ? 1 : 0;
      }
      if (rank < MIN_POS_TOPK) top10[b * MIN_POS_TOPK + rank] = mi_;
    }
  } else {
    // fallback (structurally ~never): exact 10-iteration scan
    for (int it = 0; it < MIN_POS_TOPK; ++it) {
      float bv = -1.0f; int bi = NANCH;
      for (int n = threadIdx.x; n < NANCH; n += SEL_TPB) {
        bool skip = false;
        for (int s2 = 0; s2 < it; ++s2) if (fsel[s2] == n) skip = true;
        if (skip) continue;
        float v = mi[n];
        if (v > bv || (v == bv && n < bi)) { bv = v; bi = n; }
      }
      #pragma unroll
      for (int m = 32; m >= 1; m >>= 1) {
        float ov = __shfl_xor(bv, m, 64);
        int   oi = __shfl_xor(bi, m, 64);
        if (ov > bv || (ov == bv && oi < bi)) { bv = ov; bi = oi; }
      }
      if (lane == 0) { fsv[wid] = bv; fsi[wid] = bi; }
      __syncthreads();
      if (threadIdx.x == 0) {
        float bb = -1.0f; int bj = NANCH;
        for (int w = 0; w < SEL_TPB / 64; ++w)
          if (fsv[w] > bb || (fsv[w] == bb && fsi[w] < bj)) { bb = fsv[w]; bj = fsi[w]; }
        fsel[it] = bj;
      }
      __syncthreads();
    }
    if (threadIdx.x < MIN_POS_TOPK) top10[b * MIN_POS_TOPK + threadIdx.x] = fsel[threadIdx.x];
  }

  // ---- phase 3b: exact negative cut (bits asc, index asc) ----
  if (sub) {
    int En = eqn; if (En > EQCAP) En = EQCAP;
    int r = (int)s_k - (int)s_below;     // 1-based rank within bucket
    if (threadIdx.x == 0 && (r < 1 || r > En)) {  // overflow safety (never expected)
      vbits_out[b] = 0xFFFFFFFFu; idx_cut[b] = NANCH;
    }
    for (int e = threadIdx.x; e < En; e += SEL_TPB) {
      unsigned mb = eqb_[e]; int mi_ = eqi_[e];
      int rank = 0;
      for (int j = 0; j < En; ++j) {
        unsigned ob = eqb_[j]; int oi = eqi_[j];
        rank += (ob < mb || (ob == mb && oi < mi_)) ? 1 : 0;
      }
      if (rank == r - 1) { vbits_out[b] = mb; idx_cut[b] = mi_; }
    }
  }
}

// ---------- K3: per-anchor loss accumulation ----------
__global__ __launch_bounds__(256)
void k_loss(const float* __restrict__ cls, const float* __restrict__ reg,
            const float* __restrict__ anchors, const float* __restrict__ tb,
            const int* __restrict__ tl, const float* __restrict__ scores,
            const float* __restrict__ miou, const int* __restrict__ midx,
            const int* __restrict__ use_fb, const int* __restrict__ top10,
            const int* __restrict__ subsample, const unsigned* __restrict__ vbits,
            const int* __restrict__ idx_cut,
            float* __restrict__ sums /* [NB][3] : pos, neg, reg */) {
  int b = blockIdx.x >> 8;
  int n = ((blockIdx.x & 255) << 8) | threadIdx.x;
  __shared__ int s_top10[MIN_POS_TOPK];
  __shared__ int s_usefb, s_sub, s_cut;
  __shared__ unsigned s_vb;
  __shared__ float accp, accn, accr;
  if (threadIdx.x < MIN_POS_TOPK) s_top10[threadIdx.x] = top10[b * MIN_POS_TOPK + threadIdx.x];
  if (threadIdx.x == 0) {
    s_usefb = use_fb[b]; s_sub = subsample[b]; s_cut = idx_cut[b]; s_vb = vbits[b];
    accp = 0.0f; accn = 0.0f; accr = 0.0f;
  }
  __syncthreads();

  size_t idx = (size_t)b * NANCH + n;
  float mi = miou[idx];

  bool pos;
  if (s_usefb) {
    pos = false;
    #pragma unroll
    for (int i = 0; i < MIN_POS_TOPK; ++i) pos |= (s_top10[i] == n);
  } else {
    pos = (mi >= POS_THR);
  }
  bool neg = (mi < NEG_THR);
  bool nsel = false;
  if (neg) {
    if (!s_sub) nsel = true;
    else {
      unsigned sb = __float_as_uint(scores[idx]);
      nsel = (sb < s_vb) || (sb == s_vb && n <= s_cut);
    }
  }

  float cp = 0.0f, cn = 0.0f, rg = 0.0f;
  if (pos || nsel) {
    int mx = 0, t = 0;
    if (pos) { mx = midx[idx]; t = tl[b * NM + mx]; }
    size_t cb = ((size_t)b * NC) * NANCH + n;
    float mxl = -3.0e38f, l0 = 0.0f, lt = 0.0f;
    for (int c = 0; c < NC; ++c) {
      float l = cls[cb + (size_t)c * NANCH];
      if (c == 0) l0 = l;
      if (c == t) lt = l;
      mxl = fmaxf(mxl, l);
    }
    float se = 0.0f;
    for (int c = 0; c < NC; ++c) {
      float l = cls[cb + (size_t)c * NANCH];
      se += expf(l - mxl);
    }
    float lse = mxl + logf(se);
    if (nsel) {
      float ce = lse - l0;
      float pt = expf(-ce);
      float om = 1.0f - pt;
      cn = F_ALPHA * om * om * ce;
    }
    if (pos) {
      float ce = lse - lt;
      float pt = expf(-ce);
      float om = 1.0f - pt;
      cp = F_ALPHA * om * om * ce;
      // decode + GIoU vs matched GT
      const float4 a4 = ((const float4*)anchors)[n];
      float aw = a4.z - a4.x, ah = a4.w - a4.y;
      float acx = a4.x + 0.5f * aw, acy = a4.y + 0.5f * ah;
      size_t rb = ((size_t)b * 4) * NANCH + n;
      float rx = reg[rb];
      float ry = reg[rb + (size_t)NANCH];
      float rw = reg[rb + 2 * (size_t)NANCH];
      float rh = reg[rb + 3 * (size_t)NANCH];
      float ccx = acx + rx * aw, ccy = acy + ry * ah;
      float w = aw * expf(rw), h = ah * expf(rh);
      float d0 = ccx - 0.5f * w, d1 = ccy - 0.5f * h;
      float d2 = ccx + 0.5f * w, d3 = ccy + 0.5f * h;
      const float* g = tb + ((size_t)b * NM + mx) * 4;
      float gx1 = g[0], gy1 = g[1], gx2 = g[2], gy2 = g[3];
      float area_a = (d2 - d0) * (d3 - d1);
      float area_b = (gx2 - gx1) * (gy2 - gy1);
      float lx = fmaxf(d0, gx1), ly = fmaxf(d1, gy1);
      float rx2 = fminf(d2, gx2), ry2 = fminf(d3, gy2);
      float iw = fmaxf(rx2 - lx, 0.0f), ih = fmaxf(ry2 - ly, 0.0f);
      float inter = iw * ih;
      float uni = area_a + area_b - inter;
      float iou = inter / fmaxf(uni, 1e-7f);
      float ex1 = fminf(d0, gx1), ey1 = fminf(d1, gy1);
      float ex2 = fmaxf(d2, gx2), ey2 = fmaxf(d3, gy2);
      float ew = fmaxf(ex2 - ex1, 0.0f), eh = fmaxf(ey2 - ey1, 0.0f);
      float enc = ew * eh;
      float giou = iou - (enc - uni) / fmaxf(enc, 1e-7f);
      rg = 1.0f - giou;
    }
  }

  if (cp != 0.0f) atomicAdd(&accp, cp);
  if (cn != 0.0f) atomicAdd(&accn, cn);
  if (rg != 0.0f) atomicAdd(&accr, rg);
  __syncthreads();
  if (threadIdx.x == 0) {
    if (accp != 0.0f) atomicAdd(&sums[b * 3 + 0], accp);
    if (accn != 0.0f) atomicAdd(&sums[b * 3 + 1], accn);
    if (accr != 0.0f) atomicAdd(&sums[b * 3 + 2], accr);
  }
}

// ---------- K4: finalize (parallel, 64 threads) ----------
__global__ void k_final(const float* __restrict__ sums,
                        const int* __restrict__ total_samples,
                        const int* __restrict__ num_pos,
                        float* __restrict__ out) {
  int t = threadIdx.x;
  float cm = 0.0f, rm = 0.0f;
  if (t < NB) {
    int ts = total_samples[t]; if (ts < 1) ts = 1;
    int np = num_pos[t]; if (np < 1) np = 1;
    cm = (sums[t * 3 + 0] + sums[t * 3 + 1]) / (float)ts;
    rm = sums[t * 3 + 2] / (float)np;
  }
  #pragma unroll
  for (int m = 8; m >= 1; m >>= 1) {
    cm += __shfl_down(cm, m, 64);
    rm += __shfl_down(rm, m, 64);
  }
  if (t == 0) out[0] = cm / (float)NB + rm / (float)NB;
}

extern "C" void kernel_launch(void* const* d_in, const int* in_sizes, int n_in,
                              void* d_out, int out_size, void* d_ws, size_t ws_size,
                              hipStream_t stream) {
  const float* cls     = (const float*)d_in[0];
  const float* reg     = (const float*)d_in[1];
  const float* anchors = (const float*)d_in[2];
  const float* tb      = (const float*)d_in[3];
  const int*   tl      = (const int*)d_in[4];
  const float* scores  = (const float*)d_in[5];
  float* out = (float*)d_out;

  char* ws = (char*)d_ws;
  size_t off = 0;
  float* miou = (float*)(ws + off);            off += (size_t)4 * NB * NANCH;
  int*   midx = (int*)(ws + off);              off += (size_t)4 * NB * NANCH;
  int* scal = (int*)(ws + off);
  int* num_pos       = scal;
  int* use_fb        = scal + NB;
  int* subsample     = scal + 2 * NB;
  int* idx_cut       = scal + 3 * NB;
  unsigned* vbits    = (unsigned*)(scal + 4 * NB);
  int* total_samples = scal + 5 * NB;
  int* top10         = scal + 6 * NB;                          // NB*10
  float* sums        = (float*)(scal + 6 * NB + MIN_POS_TOPK * NB); // NB*3

  k_iou<<<NB * 128, IOU_TPB, 0, stream>>>(reg, anchors, tb, miou, midx);
  k_select<<<NB, SEL_TPB, 0, stream>>>(miou, scores, num_pos, use_fb,
                                       subsample, total_samples, top10,
                                       vbits, idx_cut, sums);
  k_loss<<<NB * 256, 256, 0, stream>>>(cls, reg, anchors, tb, tl, scores,
                                       miou, midx, use_fb, top10, subsample,
                                       vbits, idx_cut, sums);
  k_final<<<1, 64, 0, stream>>>(sums, total_samples, num_pos, out);
}